// Round 7
// baseline (276.901 us; speedup 1.0000x reference)
//
#include <hip/hip_runtime.h>
#include <math.h>

#define BB   4
#define CC   64
#define KK   64
#define DDim 16
#define HDim 64
#define WDim 64
#define SS   (DDim*HDim*WDim)   /* 65536 */
#define PLANE (HDim*WDim)       /* 4096  */
#define NCH  512                /* s-chunks per batch (chunk = 128 = 2 h-rows) */
#define TOPN 6

// col-group swizzle for [s][c] tiles: group g=c>>2 stored at (g ^ (s&15))
#define SWZ(g, s) (((g) ^ ((s) & 15)))

// ---------------------------------------------------------------------------
// Kernel A: fused conv_q/conv_k + gemm1 partials.
// Block = (b, d, hc): chunk = 2 h-rows x 64 w = 128 s of plane d.
// Phase 1: conv for 2 tensors x 64 ch -> LDS qt/kt[128][64] (swizzled cols).
//   4 iters: thread = (ct8 = tid>>3 in 0..31, sub = tid&7 -> hr in 0..1,
//   wq4 in 0..3). Each iter: one channel, 1 row x 16 w strip, 3 planes x
//   3 rows x 18-float windows (aligned b128 + 2 edge scalars), 432 FMA.
// Phase 2: 64x64 GEMM over the 128-s chunk; part[b][chunk][c][k].
// ---------------------------------------------------------------------------
__global__ __launch_bounds__(256) void fused_qk_gemm1(
    const float* __restrict__ xq, const float* __restrict__ xkv,
    const float* __restrict__ wq, const float* __restrict__ bq,
    const float* __restrict__ wk, const float* __restrict__ bk,
    float* __restrict__ part)
{
    __shared__ float qt[128*64];
    __shared__ float kt[128*64];

    int bid  = blockIdx.x;
    int work = (bid & 7) * 256 + (bid >> 3);   // bijective: 2048 = 8*256
    int b  = work >> 9;
    int d  = (work >> 5) & 15;
    int hc = work & 31;
    int h0 = hc << 1;
    int tid = threadIdx.x;

    // ---------------- phase 1: conv into LDS ----------------
    {
        const int ct8 = tid >> 3;          // 0..31
        const int sub = tid & 7;
        const int hr  = sub >> 2;          // 0..1
        const int wq4 = sub & 3;           // 0..3
        const int w0  = wq4 << 4;
        const int y   = h0 + hr;           // output row in plane

        #pragma unroll
        for (int it = 0; it < 4; ++it) {
            const int tensor = it >> 1;                 // 0:q 1:k (wave-uniform)
            const int ch = ((it & 1) << 5) + ct8;       // 0..63
            const float* src  = (tensor ? xkv : xq) + (size_t)(b*CC + ch) * SS;
            const float* wsel = (tensor ? wk : wq) + ch*27;
            const float bias  = tensor ? bk[ch] : bq[ch];
            float* tile = tensor ? kt : qt;

            float wgt[27];
            #pragma unroll
            for (int i = 0; i < 27; ++i) wgt[i] = wsel[i];

            float acc[16];
            #pragma unroll
            for (int j = 0; j < 16; ++j) acc[j] = bias;

            #pragma unroll
            for (int dz = 0; dz < 3; ++dz) {
                const int p = d + dz - 1;
                if (p < 0 || p >= DDim) continue;       // wave-uniform
                float r3[3][18];
                #pragma unroll
                for (int dy = 0; dy < 3; ++dy) {
                    const int gy = y + dy - 1;
                    if (gy >= 0 && gy < HDim) {
                        const float* rp = src + (size_t)p*PLANE + gy*WDim + w0;
                        float4 a0 = *(const float4*)(rp);
                        float4 a1 = *(const float4*)(rp + 4);
                        float4 a2 = *(const float4*)(rp + 8);
                        float4 a3 = *(const float4*)(rp + 12);
                        r3[dy][0]  = (wq4 > 0) ? rp[-1] : 0.f;
                        r3[dy][17] = (wq4 < 3) ? rp[16] : 0.f;
                        r3[dy][1]=a0.x;  r3[dy][2]=a0.y;  r3[dy][3]=a0.z;  r3[dy][4]=a0.w;
                        r3[dy][5]=a1.x;  r3[dy][6]=a1.y;  r3[dy][7]=a1.z;  r3[dy][8]=a1.w;
                        r3[dy][9]=a2.x;  r3[dy][10]=a2.y; r3[dy][11]=a2.z; r3[dy][12]=a2.w;
                        r3[dy][13]=a3.x; r3[dy][14]=a3.y; r3[dy][15]=a3.z; r3[dy][16]=a3.w;
                    } else {
                        #pragma unroll
                        for (int j = 0; j < 18; ++j) r3[dy][j] = 0.f;
                    }
                }
                #pragma unroll
                for (int dy = 0; dy < 3; ++dy) {
                    const float c0 = wgt[dz*9 + dy*3 + 0];
                    const float c1 = wgt[dz*9 + dy*3 + 1];
                    const float c2 = wgt[dz*9 + dy*3 + 2];
                    #pragma unroll
                    for (int j = 0; j < 16; ++j) {
                        float s = fmaf(c0, r3[dy][j],   acc[j]);
                        s       = fmaf(c1, r3[dy][j+1], s);
                        acc[j]  = fmaf(c2, r3[dy][j+2], s);
                    }
                }
            }
            const int g  = ch >> 2;
            const int cl = ch & 3;
            #pragma unroll
            for (int j = 0; j < 16; ++j) {
                const int s = hr*64 + w0 + j;           // 0..127
                tile[s*64 + SWZ(g, s)*4 + cl] = acc[j];
            }
        }
    }
    __syncthreads();

    // ---------------- phase 2: 64x64 GEMM over 128 s ----------------
    {
        const int c0 = (tid >> 4) << 2;    // 0..60
        const int k0 = (tid & 15) << 2;    // 0..60
        const int gq = c0 >> 2;
        const int gk = k0 >> 2;
        float acc[4][4] = {};
        #pragma unroll 8
        for (int s = 0; s < 128; ++s) {
            float4 qa = *(const float4*)&qt[s*64 + SWZ(gq, s)*4];
            float4 ka = *(const float4*)&kt[s*64 + SWZ(gk, s)*4];
            float av[4] = {qa.x, qa.y, qa.z, qa.w};
            float bv[4] = {ka.x, ka.y, ka.z, ka.w};
            #pragma unroll
            for (int i = 0; i < 4; ++i)
                #pragma unroll
                for (int j = 0; j < 4; ++j)
                    acc[i][j] = fmaf(av[i], bv[j], acc[i][j]);
        }
        float* pb = part + ((size_t)b*NCH + (d*32 + hc)) * (CC*KK);
        #pragma unroll
        for (int i = 0; i < 4; ++i)
            *(float4*)&pb[(c0+i)*KK + k0] =
                make_float4(acc[i][0], acc[i][1], acc[i][2], acc[i][3]);
    }
}

// ---------------------------------------------------------------------------
// Kernel B: reduce 512 chunk-partials -> attn logits (x 1/sqrt(64) = 0.125)
// ---------------------------------------------------------------------------
__global__ __launch_bounds__(256) void reduce_attn(
    const float* __restrict__ part, float* __restrict__ attn)
{
    int bid = blockIdx.x;            // b*64 + c
    int b = bid >> 6, c = bid & 63;
    int tid = threadIdx.x;
    int k = tid & 63, g = tid >> 6;
    float s = 0.f;
    for (int ch = g; ch < NCH; ch += 4)
        s += part[(size_t)(b*NCH + ch)*(CC*KK) + c*KK + k];
    __shared__ float red[256];
    red[tid] = s;
    __syncthreads();
    if (tid < 64) {
        float tot = red[tid] + red[tid+64] + red[tid+128] + red[tid+192];
        attn[b*CC*KK + c*KK + tid] = tot * 0.125f;
    }
}

// ---------------------------------------------------------------------------
// Kernel C: per-batch softmax over K (rows) + top-6 mask per column over C.
// Strict ">" == lax.top_k lowest-index-first tie break. Writes attn_m (out 1).
// ---------------------------------------------------------------------------
__global__ __launch_bounds__(64) void softmax_topk(
    const float* __restrict__ attn, float* __restrict__ attn_m)
{
    __shared__ float p[64*65];
    int b = blockIdx.x;
    int t = threadIdx.x;
    for (int i = 0; i < 64; ++i) p[i*65 + t] = attn[b*4096 + i*64 + t];
    __syncthreads();
    float m = -1e30f;
    for (int k = 0; k < 64; ++k) m = fmaxf(m, p[t*65 + k]);
    float sum = 0.f;
    for (int k = 0; k < 64; ++k) { float e = expf(p[t*65+k] - m); p[t*65+k] = e; sum += e; }
    float inv = 1.f / sum;
    for (int k = 0; k < 64; ++k) p[t*65+k] *= inv;
    __syncthreads();
    unsigned long long chosen = 0ull;
    #pragma unroll
    for (int pass = 0; pass < TOPN; ++pass) {
        float best = -1.f; int bi = 0;
        for (int c2 = 0; c2 < 64; ++c2) {
            float v = p[c2*65 + t];
            if (!((chosen >> c2) & 1ull) && v > best) { best = v; bi = c2; }
        }
        chosen |= 1ull << bi;
    }
    for (int c2 = 0; c2 < 64; ++c2) {
        float v = p[c2*65 + t];
        attn_m[b*4096 + c2*64 + t] = ((chosen >> c2) & 1ull) ? v : 0.f;
    }
}

// ---------------------------------------------------------------------------
// Kernel D: fused conv_v + gemm2 + residual.
// Block = (b, d, hc) chunk of 128 s. Phase 1: conv_v 64 ch -> vt[64][132]
// ([k][s], pad 4) + stage amt[64][65] ([k][c]); barrier; Phase 2:
// out[c][s] = xq[c][s] + sum_k amt[k][c] * vt[k][s].
// ---------------------------------------------------------------------------
__global__ __launch_bounds__(256) void fused_v_gemm2(
    const float* __restrict__ xkv,
    const float* __restrict__ wv, const float* __restrict__ bv,
    const float* __restrict__ attn_m, const float* __restrict__ xq,
    float* __restrict__ out)
{
    __shared__ float vt[64*132];
    __shared__ float amt[64*65];

    int bid  = blockIdx.x;
    int work = (bid & 7) * 256 + (bid >> 3);
    int b  = work >> 9;
    int d  = (work >> 5) & 15;
    int hc = work & 31;
    int h0 = hc << 1;
    int tid = threadIdx.x;

    // stage attn_m tile transposed: amt[k][c]
    #pragma unroll
    for (int i = 0; i < 16; ++i) {
        int idx = i*256 + tid;               // c*64 + k
        amt[(idx & 63)*65 + (idx >> 6)] = attn_m[b*4096 + idx];
    }

    // ---------------- phase 1: conv_v into LDS ----------------
    {
        const int ct8 = tid >> 3;          // 0..31
        const int sub = tid & 7;
        const int hr  = sub >> 2;
        const int wq4 = sub & 3;
        const int w0  = wq4 << 4;
        const int y   = h0 + hr;

        #pragma unroll
        for (int it = 0; it < 2; ++it) {
            const int ch = (it << 5) + ct8;             // 0..63
            const float* src = xkv + (size_t)(b*KK + ch) * SS;
            float wgt[27];
            #pragma unroll
            for (int i = 0; i < 27; ++i) wgt[i] = wv[ch*27 + i];
            const float bias = bv[ch];

            float acc[16];
            #pragma unroll
            for (int j = 0; j < 16; ++j) acc[j] = bias;

            #pragma unroll
            for (int dz = 0; dz < 3; ++dz) {
                const int p = d + dz - 1;
                if (p < 0 || p >= DDim) continue;
                float r3[3][18];
                #pragma unroll
                for (int dy = 0; dy < 3; ++dy) {
                    const int gy = y + dy - 1;
                    if (gy >= 0 && gy < HDim) {
                        const float* rp = src + (size_t)p*PLANE + gy*WDim + w0;
                        float4 a0 = *(const float4*)(rp);
                        float4 a1 = *(const float4*)(rp + 4);
                        float4 a2 = *(const float4*)(rp + 8);
                        float4 a3 = *(const float4*)(rp + 12);
                        r3[dy][0]  = (wq4 > 0) ? rp[-1] : 0.f;
                        r3[dy][17] = (wq4 < 3) ? rp[16] : 0.f;
                        r3[dy][1]=a0.x;  r3[dy][2]=a0.y;  r3[dy][3]=a0.z;  r3[dy][4]=a0.w;
                        r3[dy][5]=a1.x;  r3[dy][6]=a1.y;  r3[dy][7]=a1.z;  r3[dy][8]=a1.w;
                        r3[dy][9]=a2.x;  r3[dy][10]=a2.y; r3[dy][11]=a2.z; r3[dy][12]=a2.w;
                        r3[dy][13]=a3.x; r3[dy][14]=a3.y; r3[dy][15]=a3.z; r3[dy][16]=a3.w;
                    } else {
                        #pragma unroll
                        for (int j = 0; j < 18; ++j) r3[dy][j] = 0.f;
                    }
                }
                #pragma unroll
                for (int dy = 0; dy < 3; ++dy) {
                    const float c0 = wgt[dz*9 + dy*3 + 0];
                    const float c1 = wgt[dz*9 + dy*3 + 1];
                    const float c2 = wgt[dz*9 + dy*3 + 2];
                    #pragma unroll
                    for (int j = 0; j < 16; ++j) {
                        float s = fmaf(c0, r3[dy][j],   acc[j]);
                        s       = fmaf(c1, r3[dy][j+1], s);
                        acc[j]  = fmaf(c2, r3[dy][j+2], s);
                    }
                }
            }
            const int sbase = hr*64 + w0;
            #pragma unroll
            for (int j4 = 0; j4 < 4; ++j4)
                *(float4*)&vt[ch*132 + sbase + j4*4] =
                    make_float4(acc[j4*4+0], acc[j4*4+1], acc[j4*4+2], acc[j4*4+3]);
        }
    }
    __syncthreads();

    // ---------------- phase 2: out = xq + A^T V  ----------------
    {
        const int c0 = (tid >> 5) << 3;     // 0..56 (8 rows)
        const int s0 = (tid & 31) << 2;     // 0..124 (4 cols)
        float acc[8][4] = {};
        #pragma unroll 4
        for (int k = 0; k < 64; ++k) {
            float4 a0 = *(const float4*)&amt[k*65 + c0];
            float4 a1 = *(const float4*)&amt[k*65 + c0 + 4];
            float4 vv = *(const float4*)&vt[k*132 + s0];
            float av[8] = {a0.x,a0.y,a0.z,a0.w,a1.x,a1.y,a1.z,a1.w};
            float vj[4] = {vv.x,vv.y,vv.z,vv.w};
            #pragma unroll
            for (int i = 0; i < 8; ++i)
                #pragma unroll
                for (int j = 0; j < 4; ++j)
                    acc[i][j] = fmaf(av[i], vj[j], acc[i][j]);
        }
        const size_t sglob = (size_t)d*PLANE + h0*WDim + s0;
        #pragma unroll
        for (int i = 0; i < 8; ++i) {
            const size_t off = (size_t)(b*CC + c0 + i)*SS + sglob;
            float4 x = *(const float4*)&xq[off];
            *(float4*)&out[off] = make_float4(acc[i][0]+x.x, acc[i][1]+x.y,
                                              acc[i][2]+x.z, acc[i][3]+x.w);
        }
    }
}

// ---------------------------------------------------------------------------
extern "C" void kernel_launch(void* const* d_in, const int* in_sizes, int n_in,
                              void* d_out, int out_size, void* d_ws, size_t ws_size,
                              hipStream_t stream)
{
    const float* xq  = (const float*)d_in[0];
    const float* xkv = (const float*)d_in[1];
    const float* wq  = (const float*)d_in[2];
    const float* bq  = (const float*)d_in[3];
    const float* wk  = (const float*)d_in[4];
    const float* bk  = (const float*)d_in[5];
    const float* wv  = (const float*)d_in[6];
    const float* bv  = (const float*)d_in[7];
    float* out = (float*)d_out;

    // workspace: gemm1 partials (33.5 MB) + attn logits (64 KB)
    float* part = (float*)d_ws;
    float* attn = part + (size_t)BB*NCH*CC*KK;

    float* attn_m = out + (size_t)BB*CC*SS;      // output 1 (B*C*K floats)

    fused_qk_gemm1<<<BB*NCH, 256, 0, stream>>>(xq, xkv, wq, bq, wk, bk, part);
    reduce_attn   <<<BB*CC,  256, 0, stream>>>(part, attn);
    softmax_topk  <<<BB,      64, 0, stream>>>(attn, attn_m);
    fused_v_gemm2 <<<BB*NCH, 256, 0, stream>>>(xkv, wv, bv, attn_m, xq, out);
}

// Round 8
// 242.438 us; speedup vs baseline: 1.1422x; 1.1422x over previous
//
#include <hip/hip_runtime.h>
#include <math.h>

#define BB   4
#define CC   64
#define KK   64
#define DDim 16
#define HDim 64
#define WDim 64
#define SS   (DDim*HDim*WDim)   /* 65536 */
#define PLANE (HDim*WDim)       /* 4096  */
#define NCH1 256                /* gemm1 s-chunks per batch (chunk = 256) */
#define TOPN 6

// ---------------------------------------------------------------------------
// Kernel 1: depthwise 3x3x3 conv (SAME), streaming LDS-ring version.
// Block = (t, b, c): t=0 -> q, t=1 -> k AND v (shared staged window).
// grid = 2*4*64 = 512 blocks (2/CU) x 256 threads; walks d = 0..15 with a
// 4-slot LDS plane ring (64 KB). T14 async-STAGE split per step:
//   issue 4 dwordx4 loads of plane d+2 -> compute plane d from LDS ->
//   ds_write staged plane into slot (d+2)%4 (disjoint from slots d-1..d+1)
//   -> one barrier.
// LDS planes are chunk-XOR swizzled: LDS slot (row, scc) holds global chunk
// scc ^ (row & 15), so compute's 64-lane column reads spread banks (~4-way).
// w-halo via 2 ds_read_b32; h/d halos are zeros. Weights uniform -> SGPRs.
// ---------------------------------------------------------------------------
__global__ __launch_bounds__(256) void conv_kv(
    const float* __restrict__ xq, const float* __restrict__ xkv,
    const float* __restrict__ wq, const float* __restrict__ bq,
    const float* __restrict__ wk, const float* __restrict__ bk,
    const float* __restrict__ wv, const float* __restrict__ bv,
    float* __restrict__ qout, float* __restrict__ kout, float* __restrict__ vout)
{
    __shared__ float ring[4*PLANE];            // 64 KB

    // bijective XCD swizzle: 512 blocks / 8 XCDs = 64 contiguous per XCD
    int bid  = blockIdx.x;
    int work = (bid & 7) * 64 + (bid >> 3);
    int t = work >> 8;                         // 0: q, 1: k+v
    int b = (work >> 6) & 3;
    int c = work & 63;

    const float* src = (t ? xkv : xq) + (size_t)(b*CC + c) * SS;
    float wA[27], wB[27], bA, bB;
    if (t == 0) {
        #pragma unroll
        for (int i = 0; i < 27; ++i) { wA[i] = wq[c*27 + i]; wB[i] = 0.f; }
        bA = bq[c]; bB = 0.f;
    } else {
        #pragma unroll
        for (int i = 0; i < 27; ++i) { wA[i] = wk[c*27 + i]; wB[i] = wv[c*27 + i]; }
        bA = bk[c]; bB = bv[c];
    }
    float* dA = (t ? kout : qout) + (size_t)(b*CC + c) * SS;
    float* dB = vout + (size_t)(b*CC + c) * SS;

    const int tid = threadIdx.x;
    const int h   = tid >> 2;                  // 0..63 (output row)
    const int wq4 = tid & 3;                   // w-quarter
    const int w0  = wq4 << 4;                  // 0,16,32,48

    // staging maps: thread stages 4 float4 chunks; slot scc holds g-chunk
    // scc ^ (row & 15)  (self-inverse permutation within each row)
    int s_goff[4], s_loff[4];
    #pragma unroll
    for (int i = 0; i < 4; ++i) {
        int f = i*256 + tid, row = f >> 4, scc = f & 15, gcc = scc ^ (row & 15);
        s_goff[i] = row*64 + gcc*4;
        s_loff[i] = row*64 + scc*4;
    }

    float4 stg[4];
#define SLOAD(p) {                                                             \
    const float* ps_ = src + (size_t)(p)*PLANE;                                \
    _Pragma("unroll")                                                          \
    for (int i_ = 0; i_ < 4; ++i_) stg[i_] = *(const float4*)(ps_ + s_goff[i_]); }
#define SWRITE(p) {                                                            \
    float* R_ = ring + ((p) & 3)*PLANE;                                        \
    _Pragma("unroll")                                                          \
    for (int i_ = 0; i_ < 4; ++i_) *(float4*)&R_[s_loff[i_]] = stg[i_]; }

    SLOAD(0); SWRITE(0);
    SLOAD(1); SWRITE(1);
    __syncthreads();

    for (int d = 0; d < DDim; ++d) {
        const bool pre = (d + 2 < DDim);
        if (pre) SLOAD(d + 2);                 // issue early (T14)

        float accA[16], accB[16];
        #pragma unroll
        for (int j = 0; j < 16; ++j) { accA[j] = bA; accB[j] = bB; }

        #pragma unroll
        for (int dz = 0; dz < 3; ++dz) {
            const int p = d + dz - 1;
            if (p < 0 || p >= DDim) continue;  // block-uniform
            const float* R = ring + (p & 3)*PLANE;
            #pragma unroll
            for (int dy = 0; dy < 3; ++dy) {
                const int gy = h + dy - 1;
                float r[18];
                if (gy >= 0 && gy < HDim) {    // divergent only at h = 0 / 63
                    const int rx = gy & 15;
                    const float* RB = R + gy*64;
                    #pragma unroll
                    for (int i = 0; i < 4; ++i) {
                        float4 a = *(const float4*)&RB[((((wq4<<2)+i) ^ rx) << 2)];
                        r[1+4*i]=a.x; r[2+4*i]=a.y; r[3+4*i]=a.z; r[4+4*i]=a.w;
                    }
                    r[0]  = wq4       ? RB[((((wq4<<2)-1) ^ rx) << 2) + 3] : 0.f;
                    r[17] = (wq4 < 3) ? RB[((((wq4<<2)+4) ^ rx) << 2)]     : 0.f;
                } else {
                    #pragma unroll
                    for (int j = 0; j < 18; ++j) r[j] = 0.f;
                }
                const float ca0 = wA[dz*9 + dy*3 + 0];
                const float ca1 = wA[dz*9 + dy*3 + 1];
                const float ca2 = wA[dz*9 + dy*3 + 2];
                const float cb0 = wB[dz*9 + dy*3 + 0];
                const float cb1 = wB[dz*9 + dy*3 + 1];
                const float cb2 = wB[dz*9 + dy*3 + 2];
                #pragma unroll
                for (int j = 0; j < 16; ++j) {
                    float sA = fmaf(ca0, r[j],   accA[j]);
                    sA       = fmaf(ca1, r[j+1], sA);
                    accA[j]  = fmaf(ca2, r[j+2], sA);
                    float sB = fmaf(cb0, r[j],   accB[j]);
                    sB       = fmaf(cb1, r[j+1], sB);
                    accB[j]  = fmaf(cb2, r[j+2], sB);
                }
            }
        }

        const int off = d*PLANE + h*WDim + w0;
        *(float4*)&dA[off+0]  = make_float4(accA[0], accA[1], accA[2], accA[3]);
        *(float4*)&dA[off+4]  = make_float4(accA[4], accA[5], accA[6], accA[7]);
        *(float4*)&dA[off+8]  = make_float4(accA[8], accA[9], accA[10],accA[11]);
        *(float4*)&dA[off+12] = make_float4(accA[12],accA[13],accA[14],accA[15]);
        if (t) {
            *(float4*)&dB[off+0]  = make_float4(accB[0], accB[1], accB[2], accB[3]);
            *(float4*)&dB[off+4]  = make_float4(accB[4], accB[5], accB[6], accB[7]);
            *(float4*)&dB[off+8]  = make_float4(accB[8], accB[9], accB[10],accB[11]);
            *(float4*)&dB[off+12] = make_float4(accB[12],accB[13],accB[14],accB[15]);
        }

        if (pre) SWRITE(d + 2);                // write late; slot (d+2)%4 is
        __syncthreads();                       // disjoint from d-1..d+1
    }
#undef SLOAD
#undef SWRITE
}

// ---------------------------------------------------------------------------
// Kernel 2: attn partials. Per block: one batch, one 256-s chunk.
// LDS tiles stored [s][c] (pad 68) so inner loop reads are uniform-row
// ds_read_b128 (conflict-free broadcast groups). 128 threads, 4x8 per thread.
// ---------------------------------------------------------------------------
__global__ __launch_bounds__(128) void gemm1_qk(
    const float* __restrict__ q, const float* __restrict__ kk, float* __restrict__ part)
{
    __shared__ float qt[64][68];
    __shared__ float kt[64][68];
    int bid = blockIdx.x;
    int b  = bid >> 8;
    int ch = bid & 255;
    int tid = threadIdx.x;
    const float* qb = q  + (size_t)b*CC*SS;
    const float* kb = kk + (size_t)b*KK*SS;
    int c0  = (tid >> 3) * 4;     // 0..60
    int k0  = (tid & 7) * 8;      // 0..56
    int ls4 = (tid & 15) * 4;     // loader: s offset
    int lcg = tid >> 4;           // loader: c group 0..7
    float acc[4][8] = {};
    int sbase0 = ch * 256;
    for (int st = 0; st < 4; ++st) {
        int sb = sbase0 + st*64;
        __syncthreads();
        #pragma unroll
        for (int i = 0; i < 8; ++i) {
            int cc2 = lcg*8 + i;
            float4 qv = *(const float4*)&qb[cc2*SS + sb + ls4];
            float4 kv = *(const float4*)&kb[cc2*SS + sb + ls4];
            qt[ls4+0][cc2] = qv.x; qt[ls4+1][cc2] = qv.y; qt[ls4+2][cc2] = qv.z; qt[ls4+3][cc2] = qv.w;
            kt[ls4+0][cc2] = kv.x; kt[ls4+1][cc2] = kv.y; kt[ls4+2][cc2] = kv.z; kt[ls4+3][cc2] = kv.w;
        }
        __syncthreads();
        #pragma unroll 8
        for (int s = 0; s < 64; ++s) {
            float4 a  = *(const float4*)&qt[s][c0];
            float4 b0 = *(const float4*)&kt[s][k0];
            float4 b1 = *(const float4*)&kt[s][k0+4];
            float av[4] = {a.x, a.y, a.z, a.w};
            float bv[8] = {b0.x,b0.y,b0.z,b0.w,b1.x,b1.y,b1.z,b1.w};
            #pragma unroll
            for (int i = 0; i < 4; ++i)
                #pragma unroll
                for (int j = 0; j < 8; ++j)
                    acc[i][j] = fmaf(av[i], bv[j], acc[i][j]);
        }
    }
    float* pb = part + (size_t)(b*NCH1 + ch)*(CC*KK);
    #pragma unroll
    for (int i = 0; i < 4; ++i) {
        *(float4*)&pb[(c0+i)*KK + k0]     = make_float4(acc[i][0],acc[i][1],acc[i][2],acc[i][3]);
        *(float4*)&pb[(c0+i)*KK + k0 + 4] = make_float4(acc[i][4],acc[i][5],acc[i][6],acc[i][7]);
    }
}

// ---------------------------------------------------------------------------
// Kernel 3: reduce 256 chunk-partials -> attn logits (scaled 1/sqrt(K)=0.125)
// ---------------------------------------------------------------------------
__global__ __launch_bounds__(256) void reduce_attn(
    const float* __restrict__ part, float* __restrict__ attn)
{
    int bid = blockIdx.x;            // b*64 + c
    int b = bid >> 6, c = bid & 63;
    int tid = threadIdx.x;
    int k = tid & 63, g = tid >> 6;
    float s = 0.f;
    for (int ch = g; ch < NCH1; ch += 4)
        s += part[(size_t)(b*NCH1 + ch)*(CC*KK) + c*KK + k];
    __shared__ float red[256];
    red[tid] = s;
    __syncthreads();
    if (tid < 64) {
        float tot = red[tid] + red[tid+64] + red[tid+128] + red[tid+192];
        attn[b*CC*KK + c*KK + tid] = tot * 0.125f;
    }
}

// ---------------------------------------------------------------------------
// Kernel 4: per-batch softmax over K (rows) + top-6 mask per column over C.
// Strict ">" selection == lax.top_k lowest-index-first tie break. Writes
// attn_m (output 1) which gemm2 consumes.
// ---------------------------------------------------------------------------
__global__ __launch_bounds__(64) void softmax_topk(
    const float* __restrict__ attn, float* __restrict__ attn_m)
{
    __shared__ float p[64*65];
    int b = blockIdx.x;
    int t = threadIdx.x;
    for (int i = 0; i < 64; ++i) p[i*65 + t] = attn[b*4096 + i*64 + t];
    __syncthreads();
    // row softmax (row = t)
    float m = -1e30f;
    for (int k = 0; k < 64; ++k) m = fmaxf(m, p[t*65 + k]);
    float sum = 0.f;
    for (int k = 0; k < 64; ++k) { float e = expf(p[t*65+k] - m); p[t*65+k] = e; sum += e; }
    float inv = 1.f / sum;
    for (int k = 0; k < 64; ++k) p[t*65+k] *= inv;
    __syncthreads();
    // top-6 per column (column = t)
    unsigned long long chosen = 0ull;
    #pragma unroll
    for (int pass = 0; pass < TOPN; ++pass) {
        float best = -1.f; int bi = 0;
        for (int c2 = 0; c2 < 64; ++c2) {
            float v = p[c2*65 + t];
            if (!((chosen >> c2) & 1ull) && v > best) { best = v; bi = c2; }
        }
        chosen |= 1ull << bi;
    }
    for (int c2 = 0; c2 < 64; ++c2) {
        float v = p[c2*65 + t];
        attn_m[b*4096 + c2*64 + t] = ((chosen >> c2) & 1ull) ? v : 0.f;
    }
}

// ---------------------------------------------------------------------------
// Kernel 5: out = x_q + attn_m @ v. Per block: one batch, 512-s chunk
// (4 subtiles of 128). attn_m held transposed [k][c] in LDS for b128 reads.
// ---------------------------------------------------------------------------
__global__ __launch_bounds__(256) void gemm2_out(
    const float* __restrict__ attn_m, const float* __restrict__ v,
    const float* __restrict__ xq, float* __restrict__ out)
{
    __shared__ float amt[64][68];    // [k][c]
    __shared__ float vt[64][132];    // [k][s]
    int bid = blockIdx.x;
    int b  = bid >> 7;
    int ch = bid & 127;
    int tid = threadIdx.x;
    for (int i = 0; i < 16; ++i) {
        int idx = i*256 + tid;                 // idx = c*64 + k
        amt[idx & 63][idx >> 6] = attn_m[b*4096 + idx];
    }
    int c0 = (tid >> 4) * 4;      // 0..60
    int s0 = (tid & 15) * 8;      // 0..120
    const float* vb = v  + (size_t)b*KK*SS;
    const float* xb = xq + (size_t)b*CC*SS;
    float* ob = out + (size_t)b*CC*SS;
    int sb0 = ch * 512;
    for (int st = 0; st < 4; ++st) {
        int sb = sb0 + st*128;
        __syncthreads();
        #pragma unroll
        for (int i = 0; i < 8; ++i) {
            int k  = (tid >> 5)*8 + i;
            int s4 = (tid & 31)*4;
            *(float4*)&vt[k][s4] = *(const float4*)&vb[k*SS + sb + s4];
        }
        __syncthreads();
        float acc[4][8] = {};
        #pragma unroll 8
        for (int k = 0; k < 64; ++k) {
            float4 a  = *(const float4*)&amt[k][c0];
            float4 v0 = *(const float4*)&vt[k][s0];
            float4 v1 = *(const float4*)&vt[k][s0+4];
            float av[4] = {a.x,a.y,a.z,a.w};
            float vv[8] = {v0.x,v0.y,v0.z,v0.w,v1.x,v1.y,v1.z,v1.w};
            #pragma unroll
            for (int i = 0; i < 4; ++i)
                #pragma unroll
                for (int j = 0; j < 8; ++j)
                    acc[i][j] = fmaf(av[i], vv[j], acc[i][j]);
        }
        #pragma unroll
        for (int i = 0; i < 4; ++i) {
            int off = (c0+i)*SS + sb + s0;
            float4 x0 = *(const float4*)&xb[off];
            float4 x1 = *(const float4*)&xb[off+4];
            *(float4*)&ob[off]   = make_float4(acc[i][0]+x0.x, acc[i][1]+x0.y,
                                               acc[i][2]+x0.z, acc[i][3]+x0.w);
            *(float4*)&ob[off+4] = make_float4(acc[i][4]+x1.x, acc[i][5]+x1.y,
                                               acc[i][6]+x1.z, acc[i][7]+x1.w);
        }
    }
}

// ---------------------------------------------------------------------------
extern "C" void kernel_launch(void* const* d_in, const int* in_sizes, int n_in,
                              void* d_out, int out_size, void* d_ws, size_t ws_size,
                              hipStream_t stream)
{
    const float* xq  = (const float*)d_in[0];
    const float* xkv = (const float*)d_in[1];
    const float* wq  = (const float*)d_in[2];
    const float* bq  = (const float*)d_in[3];
    const float* wk  = (const float*)d_in[4];
    const float* bk  = (const float*)d_in[5];
    const float* wv  = (const float*)d_in[6];
    const float* bv  = (const float*)d_in[7];
    float* out = (float*)d_out;

    // workspace: k, v, gemm1 partials, attn logits  (~145 MiB)
    float* k_ws = (float*)d_ws;
    float* v_ws = k_ws + (size_t)BB*KK*SS;
    float* part = v_ws + (size_t)BB*KK*SS;
    float* attn = part + (size_t)BB*NCH1*CC*KK;

    float* q_store = out;                        // q lives in output-0 region,
                                                 // overwritten by gemm2_out
    float* attn_m  = out + (size_t)BB*CC*SS;     // output 1 (B*C*K floats)

    conv_kv    <<<2*BB*CC,   256, 0, stream>>>(xq, xkv, wq, bq, wk, bk, wv, bv,
                                               q_store, k_ws, v_ws);
    gemm1_qk   <<<BB*NCH1,   128, 0, stream>>>(q_store, k_ws, part);
    reduce_attn<<<BB*CC,     256, 0, stream>>>(part, attn);
    softmax_topk<<<BB,        64, 0, stream>>>(attn, attn_m);
    gemm2_out  <<<BB*128,    256, 0, stream>>>(attn_m, v_ws, xq, out);
}